// Round 1
// baseline (328.571 us; speedup 1.0000x reference)
//
#include <hip/hip_runtime.h>
#include <hip/hip_bf16.h>

// z[b,n] = (1/196) * sum_{c,c'} (Xf[b] Yf[b]^T)[c,c'] * (w0[n] w1[n]^T)[c,c'] ; out = softmax_n(z + bias)
// Stage 1: M[b] = Xf Yf^T (bf16, scaled 1/196)  -> ws[0 .. 75.5MB)
// Stage 2: W[n] = w0 w1^T (bf16)                -> ws[75.5 .. 151MB)
// Stage 3: split-K dot  z partials (f32)        -> ws[151 .. 167.8MB)
// Stage 4: reduce + bias + softmax              -> d_out (f32, 64x64)

typedef float f32x4 __attribute__((ext_vector_type(4)));
typedef __bf16 bf16x8 __attribute__((ext_vector_type(8)));
typedef __bf16 bf16x4 __attribute__((ext_vector_type(4)));

#define C_DIM 768
#define KFLAT ((size_t)(768 * 768))

// Generic "A * B^T" bf16 MFMA GEMM: Out[batch][row][col] = scale * sum_p A[batch][row][p] * B[batch][col][p]
// A,B are f32, row-major with leading dim lda; plim = valid p count (rest zero-padded); ksteps*32 >= plim.
__global__ __launch_bounds__(256) void gram_bf16(
    const float* __restrict__ A, const float* __restrict__ B,
    __bf16* __restrict__ Out,
    int lda, int plim, int ksteps,
    size_t strideAB, float scale)
{
    __shared__ __bf16 As[128][32];
    __shared__ __bf16 Bs[128][32];

    const int t    = threadIdx.x;
    const int lane = t & 63;
    const int wid  = t >> 6;
    const int wr   = wid >> 1;        // 0..1 : wave row quadrant
    const int wc   = wid & 1;         // 0..1 : wave col quadrant
    const int lr   = lane & 15;
    const int lq   = lane >> 4;       // 0..3

    const int bx  = blockIdx.x;       // 0..35
    const int bat = blockIdx.y;
    const int c0  = (bx / 6) * 128;   // output row tile
    const int cc0 = (bx % 6) * 128;   // output col tile

    const float* Ab = A + (size_t)bat * strideAB;
    const float* Bb = B + (size_t)bat * strideAB;

    f32x4 zero4 = {0.f, 0.f, 0.f, 0.f};
    f32x4 acc[4][4];
#pragma unroll
    for (int i = 0; i < 4; ++i)
#pragma unroll
        for (int j = 0; j < 4; ++j) acc[i][j] = zero4;

    const int srow = t >> 3;          // 0..31
    const int scol = (t & 7) * 4;     // 0,4,...,28

    for (int kk = 0; kk < ksteps; ++kk) {
        const int kbase = kk * 32;
        __syncthreads();
#pragma unroll
        for (int it = 0; it < 4; ++it) {
            const int row = it * 32 + srow;       // tile row 0..127
            const int p   = kbase + scol;
            f32x4 va = zero4, vb = zero4;
            if (p + 4 <= plim) {
                va = *(const f32x4*)(Ab + (size_t)(c0  + row) * lda + p);
                vb = *(const f32x4*)(Bb + (size_t)(cc0 + row) * lda + p);
            }
            bf16x4 ba = { (__bf16)va.x, (__bf16)va.y, (__bf16)va.z, (__bf16)va.w };
            bf16x4 bb = { (__bf16)vb.x, (__bf16)vb.y, (__bf16)vb.z, (__bf16)vb.w };
            *(bf16x4*)&As[row][scol] = ba;
            *(bf16x4*)&Bs[row][scol] = bb;
        }
        __syncthreads();

        bf16x8 af[4], bfr[4];
#pragma unroll
        for (int m = 0; m < 4; ++m)
            af[m] = *(const bf16x8*)&As[wr * 64 + m * 16 + lr][lq * 8];
#pragma unroll
        for (int n = 0; n < 4; ++n)
            bfr[n] = *(const bf16x8*)&Bs[wc * 64 + n * 16 + lr][lq * 8];
#pragma unroll
        for (int m = 0; m < 4; ++m)
#pragma unroll
            for (int n = 0; n < 4; ++n)
                acc[m][n] = __builtin_amdgcn_mfma_f32_16x16x32_bf16(af[m], bfr[n], acc[m][n], 0, 0, 0);
    }

    __bf16* Ob = Out + (size_t)bat * KFLAT;
#pragma unroll
    for (int m = 0; m < 4; ++m) {
#pragma unroll
        for (int n = 0; n < 4; ++n) {
#pragma unroll
            for (int e = 0; e < 4; ++e) {
                const int row = c0  + wr * 64 + m * 16 + lq * 4 + e;  // D: row=(lane>>4)*4+reg
                const int col = cc0 + wc * 64 + n * 16 + lr;          // D: col=lane&15
                Ob[(size_t)row * C_DIM + col] = (__bf16)(acc[m][n][e] * scale);
            }
        }
    }
}

// Split-K: one wave per block; partial z (64x64) for its K-chunk, written to P[blk*4096 + ...]
__global__ __launch_bounds__(64) void zpartial(
    const __bf16* __restrict__ M, const __bf16* __restrict__ W,
    float* __restrict__ P, int steps)
{
    const int lane = threadIdx.x;
    const int lr = lane & 15, lq = lane >> 4;
    const size_t KK = KFLAT;  // 589824

    f32x4 zero4 = {0.f, 0.f, 0.f, 0.f};
    f32x4 acc[4][4];
#pragma unroll
    for (int i = 0; i < 4; ++i)
#pragma unroll
        for (int j = 0; j < 4; ++j) acc[i][j] = zero4;

    const size_t s0 = (size_t)blockIdx.x * steps;
    for (int s = 0; s < steps; ++s) {
        const size_t k = (s0 + s) * 32 + (size_t)lq * 8;
        bf16x8 a[4], b[4];
#pragma unroll
        for (int i = 0; i < 4; ++i) a[i] = *(const bf16x8*)(M + (size_t)(i * 16 + lr) * KK + k);
#pragma unroll
        for (int j = 0; j < 4; ++j) b[j] = *(const bf16x8*)(W + (size_t)(j * 16 + lr) * KK + k);
#pragma unroll
        for (int i = 0; i < 4; ++i)
#pragma unroll
            for (int j = 0; j < 4; ++j)
                acc[i][j] = __builtin_amdgcn_mfma_f32_16x16x32_bf16(a[i], b[j], acc[i][j], 0, 0, 0);
    }

    float* Pb = P + (size_t)blockIdx.x * 4096;
#pragma unroll
    for (int i = 0; i < 4; ++i)
#pragma unroll
        for (int j = 0; j < 4; ++j)
#pragma unroll
            for (int e = 0; e < 4; ++e) {
                const int row = i * 16 + lq * 4 + e;
                const int col = j * 16 + lr;
                Pb[row * 64 + col] = acc[i][j][e];
            }
}

// Reduce partials, add bias, softmax over n (64 lanes = one wave per b-row)
__global__ __launch_bounds__(64) void finalize(
    const float* __restrict__ P, const float* __restrict__ bias,
    float* __restrict__ out, int nchunks)
{
    const int b = blockIdx.x, n = threadIdx.x;
    float s = 0.f;
    const float* p = P + b * 64 + n;
#pragma unroll 8
    for (int c = 0; c < nchunks; ++c) s += p[(size_t)c * 4096];
    float z = s + bias[n];

    float mx = z;
#pragma unroll
    for (int off = 32; off; off >>= 1) mx = fmaxf(mx, __shfl_xor(mx, off));
    float e = __expf(z - mx);
    float den = e;
#pragma unroll
    for (int off = 32; off; off >>= 1) den += __shfl_xor(den, off);
    out[b * 64 + n] = e / den;
}

extern "C" void kernel_launch(void* const* d_in, const int* in_sizes, int n_in,
                              void* d_out, int out_size, void* d_ws, size_t ws_size,
                              hipStream_t stream) {
    const float* X    = (const float*)d_in[0];  // [64,768,14,14]
    const float* Y    = (const float*)d_in[1];  // [64,768,14,14]
    const float* w    = (const float*)d_in[2];  // [2,64,768,32]
    const float* bias = (const float*)d_in[3];  // [64]
    float* out = (float*)d_out;                 // [64,64] f32

    char* ws = (char*)d_ws;
    __bf16* Mws = (__bf16*)ws;                           // 64*768*768*2 = 75,497,472 B
    __bf16* Wws = (__bf16*)(ws + 75497472);              // 75,497,472 B
    float*  Pws = (float*)(ws + 150994944);              // 1024*4096*4 = 16,777,216 B

    // Stage 1: M[b] = X Y^T / 196   (P=196 padded to K=224)
    dim3 g1(36, 64);
    gram_bf16<<<g1, 256, 0, stream>>>(X, Y, Mws, 196, 196, 7,
                                      (size_t)768 * 196, 1.0f / 196.0f);
    // Stage 2: W[n] = w0 w1^T  (K=R=32)
    const float* w0 = w;
    const float* w1 = w + (size_t)64 * 768 * 32;
    gram_bf16<<<g1, 256, 0, stream>>>(w0, w1, Wws, 32, 32, 1,
                                      (size_t)768 * 32, 1.0f);
    // Stage 3: split-K z partials: 18432 k-steps over 1024 blocks
    zpartial<<<1024, 64, 0, stream>>>(Mws, Wws, Pws, 18);
    // Stage 4: reduce + bias + softmax
    finalize<<<64, 64, 0, stream>>>(Pws, bias, out, 1024);
}

// Round 2
// 282.680 us; speedup vs baseline: 1.1623x; 1.1623x over previous
//
#include <hip/hip_runtime.h>
#include <hip/hip_bf16.h>

// z[b,n] = (1/196) * sum_{c,c'} (Xf[b] Yf[b]^T)[c,c'] * (w0[n] w1[n]^T)[c,c'] ; out = softmax_n(z + bias)
// Stage 1: M[b] = Xf Yf^T (bf16, scaled 1/196)  -> ws[0 .. 75.5MB)     [XCD-swizzled grid]
// Stage 2: W[n] = w0 w1^T (bf16)                -> ws[75.5 .. 151MB)
// Stage 3: split-K dot  z partials (f32)        -> ws[151 .. 159.4MB)  [512 blk x 4 waves, LDS reduce]
// Stage 4: reduce + bias + softmax              -> d_out (f32, 64x64)

typedef float f32x4 __attribute__((ext_vector_type(4)));
typedef __bf16 bf16x8 __attribute__((ext_vector_type(8)));
typedef __bf16 bf16x4 __attribute__((ext_vector_type(4)));

#define C_DIM 768
#define KFLAT ((size_t)(768 * 768))

// "A * B^T" bf16 MFMA GEMM: Out[batch][row][col] = scale * sum_p A[batch][row][p] * B[batch][col][p]
// SWZ=true: 1D grid of 2304 blocks, XCD-swizzled so each XCD owns contiguous batches
// (batch inputs ~1.2MB -> L2-resident per XCD; kills the 4.2x over-fetch seen in round 1).
template<bool SWZ>
__global__ __launch_bounds__(256) void gram_bf16(
    const float* __restrict__ A, const float* __restrict__ B,
    __bf16* __restrict__ Out,
    int lda, int plim, int ksteps,
    size_t strideAB, float scale)
{
    __shared__ __bf16 As[128][32];
    __shared__ __bf16 Bs[128][32];

    const int t    = threadIdx.x;
    const int lane = t & 63;
    const int wid  = t >> 6;
    const int wr   = wid >> 1;        // 0..1 : wave row quadrant
    const int wc   = wid & 1;         // 0..1 : wave col quadrant
    const int lr   = lane & 15;
    const int lq   = lane >> 4;       // 0..3

    int bx, bat;
    if (SWZ) {
        // 2304 blocks: bid%8 = XCD; give each XCD 288 contiguous (batch-major) blocks.
        const int bid  = blockIdx.x;
        const int orig = (bid & 7) * 288 + (bid >> 3);
        bat = orig / 36;
        bx  = orig % 36;
    } else {
        bx  = blockIdx.x;             // 0..35
        bat = blockIdx.y;
    }
    const int c0  = (bx / 6) * 128;   // output row tile
    const int cc0 = (bx % 6) * 128;   // output col tile

    const float* Ab = A + (size_t)bat * strideAB;
    const float* Bb = B + (size_t)bat * strideAB;

    f32x4 zero4 = {0.f, 0.f, 0.f, 0.f};
    f32x4 acc[4][4];
#pragma unroll
    for (int i = 0; i < 4; ++i)
#pragma unroll
        for (int j = 0; j < 4; ++j) acc[i][j] = zero4;

    const int srow = t >> 3;          // 0..31
    const int scol = (t & 7) * 4;     // 0,4,...,28

    for (int kk = 0; kk < ksteps; ++kk) {
        const int kbase = kk * 32;
        __syncthreads();
#pragma unroll
        for (int it = 0; it < 4; ++it) {
            const int row = it * 32 + srow;       // tile row 0..127
            const int p   = kbase + scol;
            f32x4 va = zero4, vb = zero4;
            if (p + 4 <= plim) {
                va = *(const f32x4*)(Ab + (size_t)(c0  + row) * lda + p);
                vb = *(const f32x4*)(Bb + (size_t)(cc0 + row) * lda + p);
            }
            bf16x4 ba = { (__bf16)va.x, (__bf16)va.y, (__bf16)va.z, (__bf16)va.w };
            bf16x4 bb = { (__bf16)vb.x, (__bf16)vb.y, (__bf16)vb.z, (__bf16)vb.w };
            *(bf16x4*)&As[row][scol] = ba;
            *(bf16x4*)&Bs[row][scol] = bb;
        }
        __syncthreads();

        bf16x8 af[4], bfr[4];
#pragma unroll
        for (int m = 0; m < 4; ++m)
            af[m] = *(const bf16x8*)&As[wr * 64 + m * 16 + lr][lq * 8];
#pragma unroll
        for (int n = 0; n < 4; ++n)
            bfr[n] = *(const bf16x8*)&Bs[wc * 64 + n * 16 + lr][lq * 8];
#pragma unroll
        for (int m = 0; m < 4; ++m)
#pragma unroll
            for (int n = 0; n < 4; ++n)
                acc[m][n] = __builtin_amdgcn_mfma_f32_16x16x32_bf16(af[m], bfr[n], acc[m][n], 0, 0, 0);
    }

    __bf16* Ob = Out + (size_t)bat * KFLAT;
#pragma unroll
    for (int m = 0; m < 4; ++m) {
#pragma unroll
        for (int n = 0; n < 4; ++n) {
#pragma unroll
            for (int e = 0; e < 4; ++e) {
                const int row = c0  + wr * 64 + m * 16 + lq * 4 + e;  // D: row=(lane>>4)*4+reg
                const int col = cc0 + wc * 64 + n * 16 + lr;          // D: col=lane&15
                Ob[(size_t)row * C_DIM + col] = (__bf16)(acc[m][n][e] * scale);
            }
        }
    }
}

// Split-K: 256-thread blocks, 4 waves each with its own K-chunk; LDS-reduce to one
// 64x64 f32 partial per block. 512 blocks * 4 waves = 2048 chunks * 9 steps * 32 = 589824.
__global__ __launch_bounds__(256) void zpartial(
    const __bf16* __restrict__ M, const __bf16* __restrict__ W,
    float* __restrict__ P, int steps)
{
    __shared__ float red[4][4096];   // 64 KB

    const int t    = threadIdx.x;
    const int lane = t & 63;
    const int wid  = t >> 6;
    const int lr = lane & 15, lq = lane >> 4;
    const size_t KK = KFLAT;  // 589824

    f32x4 zero4 = {0.f, 0.f, 0.f, 0.f};
    f32x4 acc[4][4];
#pragma unroll
    for (int i = 0; i < 4; ++i)
#pragma unroll
        for (int j = 0; j < 4; ++j) acc[i][j] = zero4;

    const size_t s0 = ((size_t)blockIdx.x * 4 + wid) * steps;
    for (int s = 0; s < steps; ++s) {
        const size_t k = (s0 + s) * 32 + (size_t)lq * 8;
        bf16x8 a[4], b[4];
#pragma unroll
        for (int i = 0; i < 4; ++i) a[i] = *(const bf16x8*)(M + (size_t)(i * 16 + lr) * KK + k);
#pragma unroll
        for (int j = 0; j < 4; ++j) b[j] = *(const bf16x8*)(W + (size_t)(j * 16 + lr) * KK + k);
#pragma unroll
        for (int i = 0; i < 4; ++i)
#pragma unroll
            for (int j = 0; j < 4; ++j)
                acc[i][j] = __builtin_amdgcn_mfma_f32_16x16x32_bf16(a[i], b[j], acc[i][j], 0, 0, 0);
    }

#pragma unroll
    for (int i = 0; i < 4; ++i)
#pragma unroll
        for (int j = 0; j < 4; ++j)
#pragma unroll
            for (int e = 0; e < 4; ++e) {
                const int row = i * 16 + lq * 4 + e;
                const int col = j * 16 + lr;
                red[wid][row * 64 + col] = acc[i][j][e];
            }
    __syncthreads();

    float* Pb = P + (size_t)blockIdx.x * 4096;
    const int o0 = t * 16;
#pragma unroll
    for (int o = 0; o < 16; o += 4) {
        f32x4 v = *(const f32x4*)&red[0][o0 + o];
        v += *(const f32x4*)&red[1][o0 + o];
        v += *(const f32x4*)&red[2][o0 + o];
        v += *(const f32x4*)&red[3][o0 + o];
        *(f32x4*)(Pb + o0 + o) = v;
    }
}

// Reduce partials, add bias, softmax over n (64 lanes = one wave per b-row)
__global__ __launch_bounds__(64) void finalize(
    const float* __restrict__ P, const float* __restrict__ bias,
    float* __restrict__ out, int nchunks)
{
    const int b = blockIdx.x, n = threadIdx.x;
    float s = 0.f;
    const float* p = P + b * 64 + n;
#pragma unroll 8
    for (int c = 0; c < nchunks; ++c) s += p[(size_t)c * 4096];
    float z = s + bias[n];

    float mx = z;
#pragma unroll
    for (int off = 32; off; off >>= 1) mx = fmaxf(mx, __shfl_xor(mx, off));
    float e = __expf(z - mx);
    float den = e;
#pragma unroll
    for (int off = 32; off; off >>= 1) den += __shfl_xor(den, off);
    out[b * 64 + n] = e / den;
}

extern "C" void kernel_launch(void* const* d_in, const int* in_sizes, int n_in,
                              void* d_out, int out_size, void* d_ws, size_t ws_size,
                              hipStream_t stream) {
    const float* X    = (const float*)d_in[0];  // [64,768,14,14]
    const float* Y    = (const float*)d_in[1];  // [64,768,14,14]
    const float* w    = (const float*)d_in[2];  // [2,64,768,32]
    const float* bias = (const float*)d_in[3];  // [64]
    float* out = (float*)d_out;                 // [64,64] f32

    char* ws = (char*)d_ws;
    __bf16* Mws = (__bf16*)ws;                           // 64*768*768*2 = 75,497,472 B
    __bf16* Wws = (__bf16*)(ws + 75497472);              // 75,497,472 B
    float*  Pws = (float*)(ws + 150994944);              // 512*4096*4 = 8,388,608 B

    // Stage 1: M[b] = X Y^T / 196   (P=196 padded to K=224), XCD-swizzled 1D grid
    gram_bf16<true><<<2304, 256, 0, stream>>>(X, Y, Mws, 196, 196, 7,
                                              (size_t)768 * 196, 1.0f / 196.0f);
    // Stage 2: W[n] = w0 w1^T  (K=R=32)
    const float* w0 = w;
    const float* w1 = w + (size_t)64 * 768 * 32;
    gram_bf16<false><<<dim3(36, 64), 256, 0, stream>>>(w0, w1, Wws, 32, 32, 1,
                                                       (size_t)768 * 32, 1.0f);
    // Stage 3: split-K z partials: 2048 wave-chunks * 9 steps
    zpartial<<<512, 256, 0, stream>>>(Mws, Wws, Pws, 9);
    // Stage 4: reduce + bias + softmax
    finalize<<<64, 64, 0, stream>>>(Pws, bias, out, 512);
}

// Round 4
// 268.668 us; speedup vs baseline: 1.2230x; 1.0522x over previous
//
#include <hip/hip_runtime.h>
#include <hip/hip_bf16.h>

// z[b,n] = (1/196) * sum_{c,c'} (Xf[b] Yf[b]^T)[c,c'] * (w0[n] w1[n]^T)[c,c'] ; out = softmax_n(z + bias)
// M and W are stored in a shared FRAG-PACKED layout (any (c,c') permutation applied to both
// preserves the trace-dot): flat = tile*16384 + wave*4096 + (m*4+n)*256 + lane*4 + e.
// Stage 1: M[b] (bf16, scaled 1/196)  -> ws[0 .. 72MiB)      gram_v3, XCD-swizzled
// Stage 2: W[n] (bf16)                -> ws[72 .. 144MiB)    gram_v3
// Stage 3: split-K partials (f32)     -> ws[144 .. 156MiB)   zpartial, row-major 64x64 per chunk
// Stage 4: reduce + bias + softmax    -> d_out (f32, 64x64)

typedef float f32x4 __attribute__((ext_vector_type(4)));
typedef __bf16 bf16x8 __attribute__((ext_vector_type(8)));
typedef __bf16 bf16x4 __attribute__((ext_vector_type(4)));

#define KFLAT ((size_t)(768 * 768))
#define LDP 40   // padded LDS row (elems): 80 B row stride -> 2-way bank aliasing (free)

// A*B^T bf16 MFMA GEMM, 128x128 tile, reg-double-buffered staging, frag-packed output.
// nfull: full 32-wide k steps (unguarded). tail: if nonzero, extra step of 4 valid k-cols
// at k=nfull*32 (rest zeroed). lda = f32 row length of A,B.
template<bool SWZ>
__global__ __launch_bounds__(256) void gram_v3(
    const float* __restrict__ A, const float* __restrict__ B,
    __bf16* __restrict__ Out,
    int lda, int nfull, int tail,
    size_t strideAB, float scale)
{
    __shared__ __bf16 As[128][LDP];
    __shared__ __bf16 Bs[128][LDP];

    const int t    = threadIdx.x;
    const int lane = t & 63;
    const int wid  = t >> 6;
    const int wr   = wid >> 1, wc = wid & 1;
    const int lr   = lane & 15, lq = lane >> 4;

    int bx, bat;
    if (SWZ) {
        const int orig = (blockIdx.x & 7) * 288 + (blockIdx.x >> 3);
        bat = orig / 36; bx = orig % 36;
    } else {
        bx = blockIdx.x; bat = blockIdx.y;
    }
    const int c0 = (bx / 6) * 128, cc0 = (bx % 6) * 128;

    const int r = t >> 1;          // staging row 0..127
    const int h = t & 1;           // k-half (16 elems)
    const float* Ap = A + (size_t)bat * strideAB + (size_t)(c0  + r) * lda + h * 16;
    const float* Bp = B + (size_t)bat * strideAB + (size_t)(cc0 + r) * lda + h * 16;

    f32x4 acc[4][4];
#pragma unroll
    for (int i = 0; i < 4; ++i)
#pragma unroll
        for (int j = 0; j < 4; ++j) acc[i][j] = (f32x4){0.f, 0.f, 0.f, 0.f};

    auto stage = [&](const f32x4* va, const f32x4* vb) {
        bf16x8 u;
#pragma unroll
        for (int e = 0; e < 4; ++e) { u[e] = (__bf16)va[0][e]; u[e+4] = (__bf16)va[1][e]; }
        *(bf16x8*)&As[r][h * 16] = u;
#pragma unroll
        for (int e = 0; e < 4; ++e) { u[e] = (__bf16)va[2][e]; u[e+4] = (__bf16)va[3][e]; }
        *(bf16x8*)&As[r][h * 16 + 8] = u;
#pragma unroll
        for (int e = 0; e < 4; ++e) { u[e] = (__bf16)vb[0][e]; u[e+4] = (__bf16)vb[1][e]; }
        *(bf16x8*)&Bs[r][h * 16] = u;
#pragma unroll
        for (int e = 0; e < 4; ++e) { u[e] = (__bf16)vb[2][e]; u[e+4] = (__bf16)vb[3][e]; }
        *(bf16x8*)&Bs[r][h * 16 + 8] = u;
    };

    auto compute = [&]() {
        bf16x8 af[4], bfr[4];
#pragma unroll
        for (int m = 0; m < 4; ++m) af[m]  = *(const bf16x8*)&As[wr * 64 + m * 16 + lr][lq * 8];
#pragma unroll
        for (int n = 0; n < 4; ++n) bfr[n] = *(const bf16x8*)&Bs[wc * 64 + n * 16 + lr][lq * 8];
#pragma unroll
        for (int m = 0; m < 4; ++m)
#pragma unroll
            for (int n = 0; n < 4; ++n)
                acc[m][n] = __builtin_amdgcn_mfma_f32_16x16x32_bf16(af[m], bfr[n], acc[m][n], 0, 0, 0);
    };

    f32x4 pa[4], pb[4], na[4], nb[4];
#pragma unroll
    for (int j = 0; j < 4; ++j) {
        pa[j] = *(const f32x4*)(Ap + j * 4); pb[j] = *(const f32x4*)(Bp + j * 4);
        na[j] = (f32x4){0.f, 0.f, 0.f, 0.f}; nb[j] = (f32x4){0.f, 0.f, 0.f, 0.f};
    }

    for (int kk = 0; kk < nfull; ++kk) {
        __syncthreads();
        stage(pa, pb);
        if (kk + 1 < nfull) {
            const int o = (kk + 1) * 32;
#pragma unroll
            for (int j = 0; j < 4; ++j) { na[j] = *(const f32x4*)(Ap + o + j * 4); nb[j] = *(const f32x4*)(Bp + o + j * 4); }
        }
        __syncthreads();
        compute();
#pragma unroll
        for (int j = 0; j < 4; ++j) { pa[j] = na[j]; pb[j] = nb[j]; }
    }

    if (tail) {  // 4 valid k-cols at nfull*32, rest zero
        __syncthreads();
        const int tr = t & 127;
        const float* src = (t < 128)
            ? (A + (size_t)bat * strideAB + (size_t)(c0  + tr) * lda + nfull * 32)
            : (B + (size_t)bat * strideAB + (size_t)(cc0 + tr) * lda + nfull * 32);
        f32x4 v = *(const f32x4*)src;
        __bf16* dst = (t < 128) ? &As[tr][0] : &Bs[tr][0];
        bf16x4 q4 = { (__bf16)v.x, (__bf16)v.y, (__bf16)v.z, (__bf16)v.w };
        bf16x4 z4; bf16x8 z8;
#pragma unroll
        for (int e = 0; e < 4; ++e) z4[e] = (__bf16)0.0f;
#pragma unroll
        for (int e = 0; e < 8; ++e) z8[e] = (__bf16)0.0f;
        *(bf16x4*)dst        = q4;
        *(bf16x4*)(dst + 4)  = z4;
        *(bf16x8*)(dst + 8)  = z8;
        *(bf16x8*)(dst + 16) = z8;
        *(bf16x8*)(dst + 24) = z8;
        __syncthreads();
        compute();
    }

    // frag-packed output: coalesced bf16x4 stores
    __bf16* Ob = Out + (size_t)bat * KFLAT + (size_t)bx * 16384 + wid * 4096 + lane * 4;
#pragma unroll
    for (int m = 0; m < 4; ++m)
#pragma unroll
        for (int n = 0; n < 4; ++n) {
            bf16x4 o = { (__bf16)(acc[m][n][0] * scale), (__bf16)(acc[m][n][1] * scale),
                         (__bf16)(acc[m][n][2] * scale), (__bf16)(acc[m][n][3] * scale) };
            *(bf16x4*)(Ob + (m * 4 + n) * 256) = o;
        }
}

// Split-K: 768 blocks x 4 waves x 6 steps (= 18432 k-steps of 32). Prefetched loads,
// 32 KB staged pairwise LDS reduce, row-major 64x64 f32 partial per block.
__global__ __launch_bounds__(256) void zpartial(
    const __bf16* __restrict__ M, const __bf16* __restrict__ W,
    float* __restrict__ P, int steps)
{
    __shared__ float red[2][4096];   // 32 KB

    const int t    = threadIdx.x;
    const int lane = t & 63;
    const int wid  = t >> 6;
    const int lr = lane & 15, lq = lane >> 4;
    const size_t KK = KFLAT;

    f32x4 acc[4][4];
#pragma unroll
    for (int i = 0; i < 4; ++i)
#pragma unroll
        for (int j = 0; j < 4; ++j) acc[i][j] = (f32x4){0.f, 0.f, 0.f, 0.f};

    const size_t s0 = ((size_t)blockIdx.x * 4 + wid) * steps;
    const __bf16* Mp = M + (size_t)lr * KK + (size_t)lq * 8 + s0 * 32;
    const __bf16* Wp = W + (size_t)lr * KK + (size_t)lq * 8 + s0 * 32;

    bf16x8 a[4], b[4], a2[4], b2[4];
#pragma unroll
    for (int i = 0; i < 4; ++i) {
        a[i] = *(const bf16x8*)(Mp + i * 16 * KK); b[i] = *(const bf16x8*)(Wp + i * 16 * KK);
        a2[i] = a[i]; b2[i] = b[i];
    }

    for (int s = 0; s < steps; ++s) {
        if (s + 1 < steps) {
            const size_t o = (size_t)(s + 1) * 32;
#pragma unroll
            for (int i = 0; i < 4; ++i) { a2[i] = *(const bf16x8*)(Mp + i * 16 * KK + o); b2[i] = *(const bf16x8*)(Wp + i * 16 * KK + o); }
        }
#pragma unroll
        for (int i = 0; i < 4; ++i)
#pragma unroll
            for (int j = 0; j < 4; ++j)
                acc[i][j] = __builtin_amdgcn_mfma_f32_16x16x32_bf16(a[i], b[j], acc[i][j], 0, 0, 0);
#pragma unroll
        for (int i = 0; i < 4; ++i) { a[i] = a2[i]; b[i] = b2[i]; }
    }

    // staged reduce: w2,w3 stash; w0,w1 add; w1 stash; w0 writes row-major
    const int fbase = lane * 4;
    if (wid >= 2) {
#pragma unroll
        for (int i = 0; i < 4; ++i)
#pragma unroll
            for (int j = 0; j < 4; ++j)
                *(f32x4*)&red[wid - 2][(i * 4 + j) * 256 + fbase] = acc[i][j];
    }
    __syncthreads();
    if (wid < 2) {
#pragma unroll
        for (int i = 0; i < 4; ++i)
#pragma unroll
            for (int j = 0; j < 4; ++j)
                acc[i][j] += *(const f32x4*)&red[wid][(i * 4 + j) * 256 + fbase];
    }
    __syncthreads();
    if (wid == 1) {
#pragma unroll
        for (int i = 0; i < 4; ++i)
#pragma unroll
            for (int j = 0; j < 4; ++j)
                *(f32x4*)&red[0][(i * 4 + j) * 256 + fbase] = acc[i][j];
    }
    __syncthreads();
    if (wid == 0) {
        float* Pb = P + (size_t)blockIdx.x * 4096;
#pragma unroll
        for (int i = 0; i < 4; ++i)
#pragma unroll
            for (int j = 0; j < 4; ++j) {
                f32x4 v = acc[i][j] + *(const f32x4*)&red[0][(i * 4 + j) * 256 + fbase];
#pragma unroll
                for (int e = 0; e < 4; ++e) {
                    const int row = i * 16 + lq * 4 + e;
                    const int col = j * 16 + lr;
                    Pb[row * 64 + col] = v[e];
                }
            }
    }
}

// Reduce partials + bias + softmax. 64 blocks (b) x 256 threads (4-way chunk split per n).
__global__ __launch_bounds__(256) void finalize(
    const float* __restrict__ P, const float* __restrict__ bias,
    float* __restrict__ out, int nchunks)
{
    __shared__ float red[4][64];
    const int b = blockIdx.x, n = threadIdx.x & 63, q = threadIdx.x >> 6;
    float s = 0.f;
    for (int c = q; c < nchunks; c += 4) s += P[(size_t)c * 4096 + b * 64 + n];
    red[q][n] = s;
    __syncthreads();
    if (q == 0) {
        float z = red[0][n] + red[1][n] + red[2][n] + red[3][n] + bias[n];
        float mx = z;
#pragma unroll
        for (int off = 32; off; off >>= 1) mx = fmaxf(mx, __shfl_xor(mx, off));
        float e = __expf(z - mx);
        float den = e;
#pragma unroll
        for (int off = 32; off; off >>= 1) den += __shfl_xor(den, off);
        out[b * 64 + n] = e / den;
    }
}

extern "C" void kernel_launch(void* const* d_in, const int* in_sizes, int n_in,
                              void* d_out, int out_size, void* d_ws, size_t ws_size,
                              hipStream_t stream) {
    const float* X    = (const float*)d_in[0];  // [64,768,14,14]
    const float* Y    = (const float*)d_in[1];  // [64,768,14,14]
    const float* w    = (const float*)d_in[2];  // [2,64,768,32]
    const float* bias = (const float*)d_in[3];  // [64]
    float* out = (float*)d_out;                 // [64,64] f32

    char* ws = (char*)d_ws;
    __bf16* Mws = (__bf16*)ws;                      // 72 MiB
    __bf16* Wws = (__bf16*)(ws + 75497472);         // 72 MiB
    float*  Pws = (float*)(ws + 150994944);         // 768*4096*4 = 12 MiB  (total 156 MiB)

    // Stage 1: M[b] = X Y^T / 196 ; K = 6*32 + 4-tail
    gram_v3<true><<<2304, 256, 0, stream>>>(X, Y, Mws, 196, 6, 1,
                                            (size_t)768 * 196, 1.0f / 196.0f);
    // Stage 2: W[n] = w0 w1^T ; K = 32, no tail
    const float* w0 = w;
    const float* w1 = w + (size_t)64 * 768 * 32;
    gram_v3<false><<<dim3(36, 64), 256, 0, stream>>>(w0, w1, Wws, 32, 1, 0,
                                                     (size_t)768 * 32, 1.0f);
    // Stage 3: split-K partials
    zpartial<<<768, 256, 0, stream>>>(Mws, Wws, Pws, 6);
    // Stage 4: reduce + bias + softmax
    finalize<<<64, 256, 0, stream>>>(Pws, bias, out, 768);
}